// Round 2
// baseline (166.978 us; speedup 1.0000x reference)
//
#include <hip/hip_runtime.h>

typedef __attribute__((ext_vector_type(8))) short bf16x8;
typedef __attribute__((ext_vector_type(4))) float f32x4;
typedef __attribute__((ext_vector_type(4))) unsigned int u32x4;
typedef __attribute__((ext_vector_type(2))) unsigned int u32x2;
typedef __attribute__((ext_vector_type(4))) unsigned short u16x4;

#define H_ 16
#define B_ 2
#define T_ 2048
#define DH_ 64
#define MD_ 1024

static __device__ inline unsigned short f2bf(float f) {  // round-nearest-even
    union { float f; unsigned u; } x; x.f = f;
    unsigned r = (x.u + 0x7fffu + ((x.u >> 16) & 1u)) >> 16;
    return (unsigned short)r;
}
// pack two fp32 -> two bf16 (truncation), lo in low short. 1 v_perm_b32.
static __device__ inline unsigned int pack_bf2(float lo, float hi) {
    return __builtin_amdgcn_perm(__float_as_uint(hi), __float_as_uint(lo), 0x07060302u);
}
static __device__ inline float fexp2(float x) {
#if __has_builtin(__builtin_amdgcn_exp2f)
    return __builtin_amdgcn_exp2f(x);   // raw v_exp_f32
#else
    return exp2f(x);
#endif
}

// ---------------------------------------------------------------------------
// Kernel 1: prep. blocks 0..1023: Wo fp32->bf16 (RNE). 1024..2047: K fp32->bf16
// (trunc, same layout). 2048..3071: V fp32 -> V^T bf16 [hb][dh][T] via LDS.
// block 3072: zero the merge flags (512 ints).
// ---------------------------------------------------------------------------
__global__ __launch_bounds__(256) void prep_k(const float* __restrict__ k,
                                              const float* __restrict__ v,
                                              const float* __restrict__ w,
                                              unsigned short* __restrict__ kb,
                                              unsigned short* __restrict__ vtb,
                                              unsigned short* __restrict__ wob,
                                              int* __restrict__ fl) {
    __shared__ __attribute__((aligned(16))) unsigned short vt64[64][64];
    const int blk = blockIdx.x;
    const int tid = threadIdx.x;
    if (blk < 1024) {
        int i = (blk * 256 + tid) * 4;
        f32x4 x = *(const f32x4*)(w + i);
        u16x4 y;
        y[0] = f2bf(x[0]); y[1] = f2bf(x[1]); y[2] = f2bf(x[2]); y[3] = f2bf(x[3]);
        *(u16x4*)(wob + i) = y;
    } else if (blk < 2048) {
        int j = blk - 1024;
        const int hb = j >> 5, s0 = (j & 31) * 64;
        const int row = tid >> 2, c = (tid & 3) * 16;
        const long off = (long)hb * (T_ * DH_) + (long)(s0 + row) * DH_ + c;
        const float* p = k + off;
        f32x4 a0 = *(const f32x4*)p;
        f32x4 a1 = *(const f32x4*)(p + 4);
        f32x4 a2 = *(const f32x4*)(p + 8);
        f32x4 a3 = *(const f32x4*)(p + 12);
        u32x4 w0, w1;
        w0[0] = pack_bf2(a0[0], a0[1]); w0[1] = pack_bf2(a0[2], a0[3]);
        w0[2] = pack_bf2(a1[0], a1[1]); w0[3] = pack_bf2(a1[2], a1[3]);
        w1[0] = pack_bf2(a2[0], a2[1]); w1[1] = pack_bf2(a2[2], a2[3]);
        w1[2] = pack_bf2(a3[0], a3[1]); w1[3] = pack_bf2(a3[2], a3[3]);
        *(u32x4*)(kb + off) = w0;
        *(u32x4*)(kb + off + 8) = w1;
    } else if (blk < 3072) {
        int j = blk - 2048;
        const int hb = j >> 5, s0 = (j & 31) * 64;
        const int vkp = tid & 31, vdg = tid >> 5;  // key-pair, dh-group
        const float* vp = v + (long)hb * (T_ * DH_) + (long)(s0 + 2 * vkp) * DH_ + vdg * 8;
        f32x4 va0 = *(const f32x4*)vp;
        f32x4 va1 = *(const f32x4*)(vp + 4);
        f32x4 vb0 = *(const f32x4*)(vp + DH_);
        f32x4 vb1 = *(const f32x4*)(vp + DH_ + 4);
#pragma unroll
        for (int jj = 0; jj < 4; jj++) {
            ((unsigned int*)&vt64[vdg * 8 + jj][0])[vkp]     = pack_bf2(va0[jj], vb0[jj]);
            ((unsigned int*)&vt64[vdg * 8 + 4 + jj][0])[vkp] = pack_bf2(va1[jj], vb1[jj]);
        }
        __syncthreads();
        const int dh = tid >> 2, kc = (tid & 3) * 16;
        u32x4 o0 = *(const u32x4*)&vt64[dh][kc];
        u32x4 o1 = *(const u32x4*)&vt64[dh][kc + 8];
        unsigned short* op = vtb + (long)hb * (DH_ * T_) + (long)dh * T_ + s0 + kc;
        *(u32x4*)op = o0;
        *(u32x4*)(op + 8) = o1;
    } else {
        // zero merge flags (re-armed every launch)
        for (int z = tid; z < 512; z += 256) fl[z] = 0;
    }
}

// ---------------------------------------------------------------------------
// Kernel 2: causal attention, split-K over key-chunks for load balance.
// SWAPPED-OPERAND form (T12 at 16x16): S^T = mfma(K,Q) puts P at fixed q=ln,
// consecutive keys per lane -> P staged as 4x ds_write_b64 (was 16x b16
// scatter); PV also swapped: O^T = mfma(V^T, P) -> packed b64 ctx stores.
// Row-sums l are lane-local VALU adds (+2 shfl_xor at end) - no ones-MFMA.
// DS ops/wave/step: 26 (was 38).
// ---------------------------------------------------------------------------
#define SE(t, lo, hi) ((unsigned)((t) | ((lo) << 8) | ((hi) << 16)))
__constant__ unsigned sched48[48] = {
    // size16
    SE(31,0,16), SE(31,16,32), SE(30,15,31), SE(15,0,16),
    // size15
    SE(30,0,15), SE(29,0,15), SE(29,15,30), SE(28,14,29), SE(14,0,15),
    // size14
    SE(28,0,14), SE(27,0,14), SE(27,14,28), SE(26,13,27), SE(13,0,14),
    // size13
    SE(26,0,13), SE(25,0,13), SE(25,13,26), SE(24,12,25), SE(12,0,13),
    // size12
    SE(24,0,12), SE(23,0,12), SE(23,12,24), SE(22,11,23), SE(11,0,12),
    // size11
    SE(22,0,11), SE(21,0,11), SE(21,11,22), SE(20,10,21), SE(10,0,11),
    // size10
    SE(20,0,10), SE(19,0,10), SE(19,10,20), SE(18,9,19), SE(9,0,10),
    // size9
    SE(18,0,9), SE(17,0,9), SE(17,9,18), SE(16,8,17), SE(8,0,9),
    // size8
    SE(16,0,8), SE(7,0,8),
    // tail
    SE(6,0,7), SE(5,0,6), SE(4,0,5), SE(3,0,4), SE(2,0,3), SE(1,0,2), SE(0,0,1)
};

__global__ __launch_bounds__(256, 4) void attn_k(const float* __restrict__ q,
                                                 const unsigned short* __restrict__ kb,
                                                 const unsigned short* __restrict__ vtb,
                                                 unsigned short* __restrict__ ctx,
                                                 float* __restrict__ Op,
                                                 float* __restrict__ lp,
                                                 int* __restrict__ fl) {
    const int i = blockIdx.x;
    const int xcd = i & 7, j = i >> 3;            // per-XCD stream of 192 blocks
    const int l = j & 3, idx = j >> 2;            // hb-within-XCD, schedule slot
    const unsigned e = sched48[idx];
    const int t  = (int)(e & 255u);
    const int lo = (int)((e >> 8) & 255u);
    const int hi = (int)(e >> 16);
    const int hb = xcd * 4 + l;                   // K/V of 4 hb stay in this XCD's L2
    const int h = hb >> 1, b = hb & 1;
    const int tid = threadIdx.x;
    const int wave = tid >> 6, lane = tid & 63;
    const int ln = lane & 15, quad = lane >> 4;

    __shared__ __attribute__((aligned(16))) unsigned short kt[64][72];    // [key][dh]
    __shared__ __attribute__((aligned(16))) unsigned short vt[64][72];    // [dh][key]
    __shared__ __attribute__((aligned(16))) unsigned short pl[4][16][72]; // per-wave P [q][key]
    __shared__ int sh_who;

    const long kbase = (long)hb * (T_ * DH_);
    const long vbase = (long)hb * (DH_ * T_);
    const int q0w = t * 64 + wave * 16;
    const int srow = tid >> 2, sc = (tid & 3) * 16;

    // Q fragment (RNE, 1/sqrt(64)*log2(e) folded -> softmax via exp2)
    bf16x8 qf0, qf1;
    {
        const float qs = 0.18033688011112042f;    // 0.125 * log2(e)
        const float* qp = q + kbase + (long)(q0w + ln) * DH_ + quad * 8;
        f32x4 a0 = *(const f32x4*)qp;
        f32x4 a1 = *(const f32x4*)(qp + 4);
        f32x4 b0 = *(const f32x4*)(qp + 32);
        f32x4 b1 = *(const f32x4*)(qp + 36);
#pragma unroll
        for (int z = 0; z < 4; z++) {
            qf0[z]   = (short)f2bf(a0[z] * qs);
            qf0[4+z] = (short)f2bf(a1[z] * qs);
            qf1[z]   = (short)f2bf(b0[z] * qs);
            qf1[4+z] = (short)f2bf(b1[z] * qs);
        }
    }

    // O^T accumulators: oT[dt][r] = O[q = q0w+ln][dh = dt*16 + quad*4 + r]
    f32x4 oT[4];
#pragma unroll
    for (int z = 0; z < 4; z++) oT[z] = f32x4{0.f, 0.f, 0.f, 0.f};
    float lsum = 0.f;   // partial row-sum for q = q0w+ln (this quad's key subset)

    // prefetch first step of this chunk
    u32x4 kr0, kr1, vr0, vr1;
    {
        const unsigned short* kp = kb + kbase + (long)(lo * 64 + srow) * DH_ + sc;
        kr0 = *(const u32x4*)kp; kr1 = *(const u32x4*)(kp + 8);
        const unsigned short* vp = vtb + vbase + (long)srow * T_ + lo * 64 + sc;
        vr0 = *(const u32x4*)vp; vr1 = *(const u32x4*)(vp + 8);
    }

#pragma unroll 1
    for (int step = lo; step < hi; step++) {
        __syncthreads();
        *(u32x4*)&kt[srow][sc]     = kr0;
        *(u32x4*)&kt[srow][sc + 8] = kr1;
        *(u32x4*)&vt[srow][sc]     = vr0;
        *(u32x4*)&vt[srow][sc + 8] = vr1;
        __syncthreads();

        if (step + 1 < hi) {
            const unsigned short* kp = kb + kbase + (long)((step + 1) * 64 + srow) * DH_ + sc;
            kr0 = *(const u32x4*)kp; kr1 = *(const u32x4*)(kp + 8);
            const unsigned short* vp = vtb + vbase + (long)srow * T_ + (step + 1) * 64 + sc;
            vr0 = *(const u32x4*)vp; vr1 = *(const u32x4*)(vp + 8);
        }

        // QK^T swapped: sa[nt][r] = S[q = q0w+ln][key = step*64 + nt*16 + quad*4 + r]
        f32x4 sa[4];
#pragma unroll
        for (int nt = 0; nt < 4; nt++) {
            bf16x8 kf0 = *(const bf16x8*)&kt[nt * 16 + ln][quad * 8];
            bf16x8 kf1 = *(const bf16x8*)&kt[nt * 16 + ln][32 + quad * 8];
            f32x4 a = f32x4{0.f, 0.f, 0.f, 0.f};
            a = __builtin_amdgcn_mfma_f32_16x16x32_bf16(kf0, qf0, a, 0, 0, 0);
            a = __builtin_amdgcn_mfma_f32_16x16x32_bf16(kf1, qf1, a, 0, 0, 0);
            sa[nt] = a;
        }

        // p = exp2(s); mask only on the diagonal step (wave-uniform branch)
        if (step == t) {
            const int qi = wave * 16 + ln;   // q within tile
#pragma unroll
            for (int nt = 0; nt < 4; nt++)
#pragma unroll
                for (int r = 0; r < 4; r++) {
                    float p = fexp2(sa[nt][r]);
                    if (nt * 16 + quad * 4 + r > qi) p = 0.f;
                    sa[nt][r] = p;
                }
        } else {
#pragma unroll
            for (int nt = 0; nt < 4; nt++)
#pragma unroll
                for (int r = 0; r < 4; r++)
                    sa[nt][r] = fexp2(sa[nt][r]);
        }

        // lane-local row-sum (q = ln): replaces ones-MFMA
#pragma unroll
        for (int nt = 0; nt < 4; nt++)
            lsum += (sa[nt][0] + sa[nt][1]) + (sa[nt][2] + sa[nt][3]);

        // P -> LDS: contiguous keys per lane -> 4x ds_write_b64 (trunc pack)
#pragma unroll
        for (int nt = 0; nt < 4; nt++) {
            u32x2 ww;
            ww[0] = pack_bf2(sa[nt][0], sa[nt][1]);
            ww[1] = pack_bf2(sa[nt][2], sa[nt][3]);
            *(u32x2*)&pl[wave][ln][nt * 16 + quad * 4] = ww;
        }

        // per-wave buffer: in-wave DS ordering + lgkmcnt, no barrier needed
        bf16x8 pf0 = *(const bf16x8*)&pl[wave][ln][quad * 8];
        bf16x8 pf1 = *(const bf16x8*)&pl[wave][ln][32 + quad * 8];

        // PV swapped: oT[dt] += V^T . P  (O^T layout)
#pragma unroll
        for (int dt = 0; dt < 4; dt++) {
            bf16x8 vf0 = *(const bf16x8*)&vt[dt * 16 + ln][quad * 8];
            bf16x8 vf1 = *(const bf16x8*)&vt[dt * 16 + ln][32 + quad * 8];
            oT[dt] = __builtin_amdgcn_mfma_f32_16x16x32_bf16(vf0, pf0, oT[dt], 0, 0, 0);
            oT[dt] = __builtin_amdgcn_mfma_f32_16x16x32_bf16(vf1, pf1, oT[dt], 0, 0, 0);
        }
    }

    // full row-sum for q = ln: reduce across quads (keys were split 4-way)
    lsum += __shfl_xor(lsum, 16);
    lsum += __shfl_xor(lsum, 32);

    const int row_g = q0w + ln;   // this lane's q row

    if (t < 16) {
        // unsplit: O / l -> ctx bf16 (RNE), 4x packed b64 stores
        float rl = __builtin_amdgcn_rcpf(lsum);
#pragma unroll
        for (int dt = 0; dt < 4; dt++) {
            u16x4 y;
            y[0] = f2bf(oT[dt][0] * rl); y[1] = f2bf(oT[dt][1] * rl);
            y[2] = f2bf(oT[dt][2] * rl); y[3] = f2bf(oT[dt][3] * rl);
            *(u16x4*)&ctx[(long)(b * T_ + row_g) * MD_ + h * 64 + dt * 16 + quad * 4] = y;
        }
    } else {
        // split tile: publish partial (agent scope), flag, loser merges
        const int c = (lo != 0) ? 1 : 0;
        const long prow = (long)(t - 16) * 64 + wave * 16 + ln;  // row in partial slab
        const long pbase = (((long)c * 32 + hb) * 1024 + prow) * 64;
#pragma unroll
        for (int dt = 0; dt < 4; dt++)
#pragma unroll
            for (int r = 0; r < 4; r++)
                __hip_atomic_store(&Op[pbase + dt * 16 + quad * 4 + r], oT[dt][r],
                                   __ATOMIC_RELAXED, __HIP_MEMORY_SCOPE_AGENT);
        if (quad == 0)
            __hip_atomic_store(&lp[((long)c * 32 + hb) * 1024 + prow], lsum,
                               __ATOMIC_RELAXED, __HIP_MEMORY_SCOPE_AGENT);
        __syncthreads();   // drains each wave's vmcnt -> partials visible at agent scope
        if (tid == 0)
            sh_who = __hip_atomic_fetch_add(&fl[hb * 16 + (t - 16)], 1,
                                            __ATOMIC_RELAXED, __HIP_MEMORY_SCOPE_AGENT);
        __syncthreads();
        if (sh_who == 1) {
            // second finisher: add partner partial (its stores happened-before its
            // flag bump, which happened-before ours returned 1)
            const long qbase = (((long)(c ^ 1) * 32 + hb) * 1024 + prow) * 64;
#pragma unroll
            for (int dt = 0; dt < 4; dt++)
#pragma unroll
                for (int r = 0; r < 4; r++)
                    oT[dt][r] += __hip_atomic_load(&Op[qbase + dt * 16 + quad * 4 + r],
                                                   __ATOMIC_RELAXED, __HIP_MEMORY_SCOPE_AGENT);
            lsum += __hip_atomic_load(&lp[((long)(c ^ 1) * 32 + hb) * 1024 + prow],
                                      __ATOMIC_RELAXED, __HIP_MEMORY_SCOPE_AGENT);
            float rl = __builtin_amdgcn_rcpf(lsum);
#pragma unroll
            for (int dt = 0; dt < 4; dt++) {
                u16x4 y;
                y[0] = f2bf(oT[dt][0] * rl); y[1] = f2bf(oT[dt][1] * rl);
                y[2] = f2bf(oT[dt][2] * rl); y[3] = f2bf(oT[dt][3] * rl);
                *(u16x4*)&ctx[(long)(b * T_ + row_g) * MD_ + h * 64 + dt * 16 + quad * 4] = y;
            }
        }
    }
}

// ---------------------------------------------------------------------------
// Kernel 3: projection GEMM. out[m][n] = ctx[m][:] . Wo[n][:] + bias[n]
// M=4096 N=1024 K=1024. BM=64 BN=64 BK=64 -> 1024 blocks (4/CU).
// XCD swizzle: each XCD owns 2 n-tiles (Wo slice 256 KB -> L2-resident).
// ---------------------------------------------------------------------------
__global__ __launch_bounds__(256, 4) void proj_k(const unsigned short* __restrict__ A,
                                                 const unsigned short* __restrict__ Bw,
                                                 const float* __restrict__ bias,
                                                 float* __restrict__ out) {
    const int i = blockIdx.x;
    const int n0 = ((i & 7) * 2 + ((i >> 3) & 1)) * 64;
    const int m0 = (i >> 4) * 64;
    const int tid = threadIdx.x;
    const int wave = tid >> 6, lane = tid & 63;
    const int ln = lane & 15, quad = lane >> 4;

    __shared__ __attribute__((aligned(16))) unsigned short As[64][72];
    __shared__ __attribute__((aligned(16))) unsigned short Bs[64][72];

    const int srow = tid >> 2, sc = (tid & 3) * 16;

    f32x4 acc[4];
#pragma unroll
    for (int z = 0; z < 4; z++) acc[z] = f32x4{0.f, 0.f, 0.f, 0.f};

    u32x4 ar0, ar1, br0, br1;
    {
        const unsigned short* ap = A + (long)(m0 + srow) * 1024 + sc;
        ar0 = *(const u32x4*)ap; ar1 = *(const u32x4*)(ap + 8);
        const unsigned short* bp = Bw + (long)(n0 + srow) * 1024 + sc;
        br0 = *(const u32x4*)bp; br1 = *(const u32x4*)(bp + 8);
    }

#pragma unroll 1
    for (int ks = 0; ks < 1024; ks += 64) {
        __syncthreads();
        *(u32x4*)&As[srow][sc]     = ar0;
        *(u32x4*)&As[srow][sc + 8] = ar1;
        *(u32x4*)&Bs[srow][sc]     = br0;
        *(u32x4*)&Bs[srow][sc + 8] = br1;
        __syncthreads();

        if (ks + 64 < 1024) {
            const unsigned short* ap = A + (long)(m0 + srow) * 1024 + ks + 64 + sc;
            ar0 = *(const u32x4*)ap; ar1 = *(const u32x4*)(ap + 8);
            const unsigned short* bp = Bw + (long)(n0 + srow) * 1024 + ks + 64 + sc;
            br0 = *(const u32x4*)bp; br1 = *(const u32x4*)(bp + 8);
        }

        bf16x8 bf0 = *(const bf16x8*)&Bs[wave * 16 + ln][quad * 8];
        bf16x8 bf1 = *(const bf16x8*)&Bs[wave * 16 + ln][32 + quad * 8];
#pragma unroll
        for (int mt = 0; mt < 4; mt++) {
            bf16x8 af0 = *(const bf16x8*)&As[mt * 16 + ln][quad * 8];
            bf16x8 af1 = *(const bf16x8*)&As[mt * 16 + ln][32 + quad * 8];
            acc[mt] = __builtin_amdgcn_mfma_f32_16x16x32_bf16(af0, bf0, acc[mt], 0, 0, 0);
            acc[mt] = __builtin_amdgcn_mfma_f32_16x16x32_bf16(af1, bf1, acc[mt], 0, 0, 0);
        }
    }

    int col = n0 + wave * 16 + ln;
    float bz = bias[col];
#pragma unroll
    for (int mt = 0; mt < 4; mt++)
#pragma unroll
        for (int r = 0; r < 4; r++) {
            int row = m0 + mt * 16 + quad * 4 + r;
            out[(long)row * 1024 + col] = acc[mt][r] + bz;
        }
}

extern "C" void kernel_launch(void* const* d_in, const int* in_sizes, int n_in,
                              void* d_out, int out_size, void* d_ws, size_t ws_size,
                              hipStream_t stream) {
    const float* q    = (const float*)d_in[0];
    const float* k    = (const float*)d_in[1];
    const float* v    = (const float*)d_in[2];
    const float* Wo_w = (const float*)d_in[3];
    const float* Wo_b = (const float*)d_in[4];
    float* out = (float*)d_out;

    unsigned short* ctx = (unsigned short*)d_ws;           // [4096][1024]   8.4 MB
    unsigned short* wob = ctx + (size_t)4096 * 1024;       // [1024][1024]   2.1 MB
    unsigned short* kbb = wob + (size_t)1024 * 1024;       // [32][2048][64] 8.4 MB
    unsigned short* vtb = kbb + (size_t)32 * 2048 * 64;    // [32][64][2048] 8.4 MB
    float* Opart = (float*)(vtb + (size_t)32 * 2048 * 64); // [2][32][1024][64] 16.8 MB
    float* lpart = Opart + (size_t)2 * 32 * 1024 * 64;     // [2][32][1024]  256 KB
    int*   flags = (int*)(lpart + (size_t)2 * 32 * 1024);  // [32][16]       2 KB

    prep_k<<<3073, 256, 0, stream>>>(k, v, Wo_w, kbb, vtb, wob, flags);
    attn_k<<<1536, 256, 0, stream>>>(q, kbb, vtb, ctx, Opart, lpart, flags);
    proj_k<<<1024, 256, 0, stream>>>(ctx, wob, Wo_b, out);
}

// Round 3
// 150.813 us; speedup vs baseline: 1.1072x; 1.1072x over previous
//
#include <hip/hip_runtime.h>

typedef __attribute__((ext_vector_type(8))) short bf16x8;
typedef __attribute__((ext_vector_type(4))) float f32x4;
typedef __attribute__((ext_vector_type(4))) unsigned int u32x4;
typedef __attribute__((ext_vector_type(2))) unsigned int u32x2;
typedef __attribute__((ext_vector_type(4))) unsigned short u16x4;

#define H_ 16
#define B_ 2
#define T_ 2048
#define DH_ 64
#define MD_ 1024

static __device__ inline unsigned short f2bf(float f) {  // round-nearest-even
    union { float f; unsigned u; } x; x.f = f;
    unsigned r = (x.u + 0x7fffu + ((x.u >> 16) & 1u)) >> 16;
    return (unsigned short)r;
}
// pack two fp32 -> two bf16 (truncation), lo in low short. 1 v_perm_b32.
static __device__ inline unsigned int pack_bf2(float lo, float hi) {
    return __builtin_amdgcn_perm(__float_as_uint(hi), __float_as_uint(lo), 0x07060302u);
}
static __device__ inline float fexp2(float x) {
#if __has_builtin(__builtin_amdgcn_exp2f)
    return __builtin_amdgcn_exp2f(x);   // raw v_exp_f32
#else
    return exp2f(x);
#endif
}

// ---------------------------------------------------------------------------
// Kernel 1: prep. blocks 0..1023: Wo fp32->bf16 (RNE). 1024..2047: K fp32->bf16
// (trunc, same layout). 2048..3071: V fp32 -> V^T bf16 [hb][dh][T] via LDS.
// block 3072: zero the merge flags (512 ints).
// ---------------------------------------------------------------------------
__global__ __launch_bounds__(256) void prep_k(const float* __restrict__ k,
                                              const float* __restrict__ v,
                                              const float* __restrict__ w,
                                              unsigned short* __restrict__ kb,
                                              unsigned short* __restrict__ vtb,
                                              unsigned short* __restrict__ wob,
                                              int* __restrict__ fl) {
    __shared__ __attribute__((aligned(16))) unsigned short vt64[64][64];
    const int blk = blockIdx.x;
    const int tid = threadIdx.x;
    if (blk < 1024) {
        int i = (blk * 256 + tid) * 4;
        f32x4 x = *(const f32x4*)(w + i);
        u16x4 y;
        y[0] = f2bf(x[0]); y[1] = f2bf(x[1]); y[2] = f2bf(x[2]); y[3] = f2bf(x[3]);
        *(u16x4*)(wob + i) = y;
    } else if (blk < 2048) {
        int j = blk - 1024;
        const int hb = j >> 5, s0 = (j & 31) * 64;
        const int row = tid >> 2, c = (tid & 3) * 16;
        const long off = (long)hb * (T_ * DH_) + (long)(s0 + row) * DH_ + c;
        const float* p = k + off;
        f32x4 a0 = *(const f32x4*)p;
        f32x4 a1 = *(const f32x4*)(p + 4);
        f32x4 a2 = *(const f32x4*)(p + 8);
        f32x4 a3 = *(const f32x4*)(p + 12);
        u32x4 w0, w1;
        w0[0] = pack_bf2(a0[0], a0[1]); w0[1] = pack_bf2(a0[2], a0[3]);
        w0[2] = pack_bf2(a1[0], a1[1]); w0[3] = pack_bf2(a1[2], a1[3]);
        w1[0] = pack_bf2(a2[0], a2[1]); w1[1] = pack_bf2(a2[2], a2[3]);
        w1[2] = pack_bf2(a3[0], a3[1]); w1[3] = pack_bf2(a3[2], a3[3]);
        *(u32x4*)(kb + off) = w0;
        *(u32x4*)(kb + off + 8) = w1;
    } else if (blk < 3072) {
        int j = blk - 2048;
        const int hb = j >> 5, s0 = (j & 31) * 64;
        const int vkp = tid & 31, vdg = tid >> 5;  // key-pair, dh-group
        const float* vp = v + (long)hb * (T_ * DH_) + (long)(s0 + 2 * vkp) * DH_ + vdg * 8;
        f32x4 va0 = *(const f32x4*)vp;
        f32x4 va1 = *(const f32x4*)(vp + 4);
        f32x4 vb0 = *(const f32x4*)(vp + DH_);
        f32x4 vb1 = *(const f32x4*)(vp + DH_ + 4);
#pragma unroll
        for (int jj = 0; jj < 4; jj++) {
            ((unsigned int*)&vt64[vdg * 8 + jj][0])[vkp]     = pack_bf2(va0[jj], vb0[jj]);
            ((unsigned int*)&vt64[vdg * 8 + 4 + jj][0])[vkp] = pack_bf2(va1[jj], vb1[jj]);
        }
        __syncthreads();
        const int dh = tid >> 2, kc = (tid & 3) * 16;
        u32x4 o0 = *(const u32x4*)&vt64[dh][kc];
        u32x4 o1 = *(const u32x4*)&vt64[dh][kc + 8];
        unsigned short* op = vtb + (long)hb * (DH_ * T_) + (long)dh * T_ + s0 + kc;
        *(u32x4*)op = o0;
        *(u32x4*)(op + 8) = o1;
    } else {
        // zero merge flags (re-armed every launch)
        for (int z = tid; z < 512; z += 256) fl[z] = 0;
    }
}

// ---------------------------------------------------------------------------
// Kernel 2: causal attention, split-K + swapped-operand MFMA (S^T = K.Q,
// O^T = V^T.P). This round: coalesced partial slab in O^T layout
// ([dh][q] -> lane-contiguous 64B segments) and ctx epilogue through a
// per-wave LDS transpose (packed 16B global stores) instead of the 2KB-
// strided 8B scatter that blew WRITE_SIZE to 74MB in round 2.
// ---------------------------------------------------------------------------
#define SE(t, lo, hi) ((unsigned)((t) | ((lo) << 8) | ((hi) << 16)))
__constant__ unsigned sched48[48] = {
    // size16
    SE(31,0,16), SE(31,16,32), SE(30,15,31), SE(15,0,16),
    // size15
    SE(30,0,15), SE(29,0,15), SE(29,15,30), SE(28,14,29), SE(14,0,15),
    // size14
    SE(28,0,14), SE(27,0,14), SE(27,14,28), SE(26,13,27), SE(13,0,14),
    // size13
    SE(26,0,13), SE(25,0,13), SE(25,13,26), SE(24,12,25), SE(12,0,13),
    // size12
    SE(24,0,12), SE(23,0,12), SE(23,12,24), SE(22,11,23), SE(11,0,12),
    // size11
    SE(22,0,11), SE(21,0,11), SE(21,11,22), SE(20,10,21), SE(10,0,11),
    // size10
    SE(20,0,10), SE(19,0,10), SE(19,10,20), SE(18,9,19), SE(9,0,10),
    // size9
    SE(18,0,9), SE(17,0,9), SE(17,9,18), SE(16,8,17), SE(8,0,9),
    // size8
    SE(16,0,8), SE(7,0,8),
    // tail
    SE(6,0,7), SE(5,0,6), SE(4,0,5), SE(3,0,4), SE(2,0,3), SE(1,0,2), SE(0,0,1)
};

__global__ __launch_bounds__(256, 4) void attn_k(const float* __restrict__ q,
                                                 const unsigned short* __restrict__ kb,
                                                 const unsigned short* __restrict__ vtb,
                                                 unsigned short* __restrict__ ctx,
                                                 float* __restrict__ Op,
                                                 float* __restrict__ lp,
                                                 int* __restrict__ fl) {
    const int i = blockIdx.x;
    const int xcd = i & 7, j = i >> 3;            // per-XCD stream of 192 blocks
    const int l = j & 3, idx = j >> 2;            // hb-within-XCD, schedule slot
    const unsigned e = sched48[idx];
    const int t  = (int)(e & 255u);
    const int lo = (int)((e >> 8) & 255u);
    const int hi = (int)(e >> 16);
    const int hb = xcd * 4 + l;                   // K/V of 4 hb stay in this XCD's L2
    const int h = hb >> 1, b = hb & 1;
    const int tid = threadIdx.x;
    const int wave = tid >> 6, lane = tid & 63;
    const int ln = lane & 15, quad = lane >> 4;

    __shared__ __attribute__((aligned(16))) unsigned short kt[64][72];    // [key][dh]
    __shared__ __attribute__((aligned(16))) unsigned short vt[64][72];    // [dh][key]
    __shared__ __attribute__((aligned(16))) unsigned short pl[4][16][72]; // per-wave P [q][key]
    __shared__ int sh_who;

    const long kbase = (long)hb * (T_ * DH_);
    const long vbase = (long)hb * (DH_ * T_);
    const int q0w = t * 64 + wave * 16;
    const int srow = tid >> 2, sc = (tid & 3) * 16;

    // Q fragment (RNE, 1/sqrt(64)*log2(e) folded -> softmax via exp2)
    bf16x8 qf0, qf1;
    {
        const float qs = 0.18033688011112042f;    // 0.125 * log2(e)
        const float* qp = q + kbase + (long)(q0w + ln) * DH_ + quad * 8;
        f32x4 a0 = *(const f32x4*)qp;
        f32x4 a1 = *(const f32x4*)(qp + 4);
        f32x4 b0 = *(const f32x4*)(qp + 32);
        f32x4 b1 = *(const f32x4*)(qp + 36);
#pragma unroll
        for (int z = 0; z < 4; z++) {
            qf0[z]   = (short)f2bf(a0[z] * qs);
            qf0[4+z] = (short)f2bf(a1[z] * qs);
            qf1[z]   = (short)f2bf(b0[z] * qs);
            qf1[4+z] = (short)f2bf(b1[z] * qs);
        }
    }

    // O^T accumulators: oT[dt][r] = O[q = q0w+ln][dh = dt*16 + quad*4 + r]
    f32x4 oT[4];
#pragma unroll
    for (int z = 0; z < 4; z++) oT[z] = f32x4{0.f, 0.f, 0.f, 0.f};
    float lsum = 0.f;   // partial row-sum for q = q0w+ln (this quad's key subset)

    // prefetch first step of this chunk
    u32x4 kr0, kr1, vr0, vr1;
    {
        const unsigned short* kp = kb + kbase + (long)(lo * 64 + srow) * DH_ + sc;
        kr0 = *(const u32x4*)kp; kr1 = *(const u32x4*)(kp + 8);
        const unsigned short* vp = vtb + vbase + (long)srow * T_ + lo * 64 + sc;
        vr0 = *(const u32x4*)vp; vr1 = *(const u32x4*)(vp + 8);
    }

#pragma unroll 1
    for (int step = lo; step < hi; step++) {
        __syncthreads();
        *(u32x4*)&kt[srow][sc]     = kr0;
        *(u32x4*)&kt[srow][sc + 8] = kr1;
        *(u32x4*)&vt[srow][sc]     = vr0;
        *(u32x4*)&vt[srow][sc + 8] = vr1;
        __syncthreads();

        if (step + 1 < hi) {
            const unsigned short* kp = kb + kbase + (long)((step + 1) * 64 + srow) * DH_ + sc;
            kr0 = *(const u32x4*)kp; kr1 = *(const u32x4*)(kp + 8);
            const unsigned short* vp = vtb + vbase + (long)srow * T_ + (step + 1) * 64 + sc;
            vr0 = *(const u32x4*)vp; vr1 = *(const u32x4*)(vp + 8);
        }

        // QK^T swapped: sa[nt][r] = S[q = q0w+ln][key = step*64 + nt*16 + quad*4 + r]
        f32x4 sa[4];
#pragma unroll
        for (int nt = 0; nt < 4; nt++) {
            bf16x8 kf0 = *(const bf16x8*)&kt[nt * 16 + ln][quad * 8];
            bf16x8 kf1 = *(const bf16x8*)&kt[nt * 16 + ln][32 + quad * 8];
            f32x4 a = f32x4{0.f, 0.f, 0.f, 0.f};
            a = __builtin_amdgcn_mfma_f32_16x16x32_bf16(kf0, qf0, a, 0, 0, 0);
            a = __builtin_amdgcn_mfma_f32_16x16x32_bf16(kf1, qf1, a, 0, 0, 0);
            sa[nt] = a;
        }

        // p = exp2(s); mask only on the diagonal step (wave-uniform branch)
        if (step == t) {
            const int qi = wave * 16 + ln;   // q within tile
#pragma unroll
            for (int nt = 0; nt < 4; nt++)
#pragma unroll
                for (int r = 0; r < 4; r++) {
                    float p = fexp2(sa[nt][r]);
                    if (nt * 16 + quad * 4 + r > qi) p = 0.f;
                    sa[nt][r] = p;
                }
        } else {
#pragma unroll
            for (int nt = 0; nt < 4; nt++)
#pragma unroll
                for (int r = 0; r < 4; r++)
                    sa[nt][r] = fexp2(sa[nt][r]);
        }

        // lane-local row-sum (q = ln): replaces ones-MFMA
#pragma unroll
        for (int nt = 0; nt < 4; nt++)
            lsum += (sa[nt][0] + sa[nt][1]) + (sa[nt][2] + sa[nt][3]);

        // P -> LDS: contiguous keys per lane -> 4x ds_write_b64 (trunc pack)
#pragma unroll
        for (int nt = 0; nt < 4; nt++) {
            u32x2 ww;
            ww[0] = pack_bf2(sa[nt][0], sa[nt][1]);
            ww[1] = pack_bf2(sa[nt][2], sa[nt][3]);
            *(u32x2*)&pl[wave][ln][nt * 16 + quad * 4] = ww;
        }

        // per-wave buffer: in-wave DS ordering + lgkmcnt, no barrier needed
        bf16x8 pf0 = *(const bf16x8*)&pl[wave][ln][quad * 8];
        bf16x8 pf1 = *(const bf16x8*)&pl[wave][ln][32 + quad * 8];

        // PV swapped: oT[dt] += V^T . P  (O^T layout)
#pragma unroll
        for (int dt = 0; dt < 4; dt++) {
            bf16x8 vf0 = *(const bf16x8*)&vt[dt * 16 + ln][quad * 8];
            bf16x8 vf1 = *(const bf16x8*)&vt[dt * 16 + ln][32 + quad * 8];
            oT[dt] = __builtin_amdgcn_mfma_f32_16x16x32_bf16(vf0, pf0, oT[dt], 0, 0, 0);
            oT[dt] = __builtin_amdgcn_mfma_f32_16x16x32_bf16(vf1, pf1, oT[dt], 0, 0, 0);
        }
    }

    // full row-sum for q = ln: reduce across quads (keys were split 4-way)
    lsum += __shfl_xor(lsum, 16);
    lsum += __shfl_xor(lsum, 32);

    float rl;
    if (t < 16) {
        rl = __builtin_amdgcn_rcpf(lsum);
    } else {
        // split tile: publish partial in O^T slab layout [dh][q] -> each scalar
        // store = quad-contiguous 64B lines (coalesced). Loser merges.
        const int c = (lo != 0) ? 1 : 0;
        const long slab = (((long)c * 32 + hb) * 16 + (t - 16));
        float* ob = Op + slab * 4096;
        const int qlocal = wave * 16 + ln;
#pragma unroll
        for (int dt = 0; dt < 4; dt++)
#pragma unroll
            for (int r = 0; r < 4; r++)
                __hip_atomic_store(&ob[(dt * 16 + quad * 4 + r) * 64 + qlocal], oT[dt][r],
                                   __ATOMIC_RELAXED, __HIP_MEMORY_SCOPE_AGENT);
        if (quad == 0)
            __hip_atomic_store(&lp[slab * 64 + qlocal], lsum,
                               __ATOMIC_RELAXED, __HIP_MEMORY_SCOPE_AGENT);
        __syncthreads();   // drains each wave's vmcnt -> partials visible at agent scope
        if (tid == 0)
            sh_who = __hip_atomic_fetch_add(&fl[hb * 16 + (t - 16)], 1,
                                            __ATOMIC_RELAXED, __HIP_MEMORY_SCOPE_AGENT);
        __syncthreads();
        if (sh_who != 1) return;   // first finisher exits; loser merges (block-uniform)
        const long slab2 = (((long)(c ^ 1) * 32 + hb) * 16 + (t - 16));
        const float* qb = Op + slab2 * 4096;
#pragma unroll
        for (int dt = 0; dt < 4; dt++)
#pragma unroll
            for (int r = 0; r < 4; r++)
                oT[dt][r] += __hip_atomic_load(&qb[(dt * 16 + quad * 4 + r) * 64 + qlocal],
                                               __ATOMIC_RELAXED, __HIP_MEMORY_SCOPE_AGENT);
        lsum += __hip_atomic_load(&lp[slab2 * 64 + qlocal],
                                  __ATOMIC_RELAXED, __HIP_MEMORY_SCOPE_AGENT);
        rl = __builtin_amdgcn_rcpf(lsum);
    }

    // epilogue: scale, pack bf16 (RNE), transpose via own-wave pl region
    // (in-wave DS ordering, no barrier), then coalesced 16B ctx stores.
#pragma unroll
    for (int dt = 0; dt < 4; dt++) {
        u16x4 y;
        y[0] = f2bf(oT[dt][0] * rl); y[1] = f2bf(oT[dt][1] * rl);
        y[2] = f2bf(oT[dt][2] * rl); y[3] = f2bf(oT[dt][3] * rl);
        *(u16x4*)&pl[wave][ln][dt * 16 + quad * 4] = y;
    }
    const int rr = lane >> 2, cc = (lane & 3) * 16;
    u32x4 z0 = *(const u32x4*)&pl[wave][rr][cc];
    u32x4 z1 = *(const u32x4*)&pl[wave][rr][cc + 8];
    unsigned short* cp = ctx + (long)(b * T_ + t * 64 + wave * 16 + rr) * MD_ + h * 64 + cc;
    *(u32x4*)cp = z0;
    *(u32x4*)(cp + 8) = z1;
}

// ---------------------------------------------------------------------------
// Kernel 3: projection GEMM. out[m][n] = ctx[m][:] . Wo[n][:] + bias[n]
// M=4096 N=1024 K=1024. BM=64 BN=64 BK=64 -> 1024 blocks (4/CU).
// XCD swizzle: each XCD owns 2 n-tiles (Wo slice 256 KB -> L2-resident).
// ---------------------------------------------------------------------------
__global__ __launch_bounds__(256, 4) void proj_k(const unsigned short* __restrict__ A,
                                                 const unsigned short* __restrict__ Bw,
                                                 const float* __restrict__ bias,
                                                 float* __restrict__ out) {
    const int i = blockIdx.x;
    const int n0 = ((i & 7) * 2 + ((i >> 3) & 1)) * 64;
    const int m0 = (i >> 4) * 64;
    const int tid = threadIdx.x;
    const int wave = tid >> 6, lane = tid & 63;
    const int ln = lane & 15, quad = lane >> 4;

    __shared__ __attribute__((aligned(16))) unsigned short As[64][72];
    __shared__ __attribute__((aligned(16))) unsigned short Bs[64][72];

    const int srow = tid >> 2, sc = (tid & 3) * 16;

    f32x4 acc[4];
#pragma unroll
    for (int z = 0; z < 4; z++) acc[z] = f32x4{0.f, 0.f, 0.f, 0.f};

    u32x4 ar0, ar1, br0, br1;
    {
        const unsigned short* ap = A + (long)(m0 + srow) * 1024 + sc;
        ar0 = *(const u32x4*)ap; ar1 = *(const u32x4*)(ap + 8);
        const unsigned short* bp = Bw + (long)(n0 + srow) * 1024 + sc;
        br0 = *(const u32x4*)bp; br1 = *(const u32x4*)(bp + 8);
    }

#pragma unroll 1
    for (int ks = 0; ks < 1024; ks += 64) {
        __syncthreads();
        *(u32x4*)&As[srow][sc]     = ar0;
        *(u32x4*)&As[srow][sc + 8] = ar1;
        *(u32x4*)&Bs[srow][sc]     = br0;
        *(u32x4*)&Bs[srow][sc + 8] = br1;
        __syncthreads();

        if (ks + 64 < 1024) {
            const unsigned short* ap = A + (long)(m0 + srow) * 1024 + ks + 64 + sc;
            ar0 = *(const u32x4*)ap; ar1 = *(const u32x4*)(ap + 8);
            const unsigned short* bp = Bw + (long)(n0 + srow) * 1024 + ks + 64 + sc;
            br0 = *(const u32x4*)bp; br1 = *(const u32x4*)(bp + 8);
        }

        bf16x8 bf0 = *(const bf16x8*)&Bs[wave * 16 + ln][quad * 8];
        bf16x8 bf1 = *(const bf16x8*)&Bs[wave * 16 + ln][32 + quad * 8];
#pragma unroll
        for (int mt = 0; mt < 4; mt++) {
            bf16x8 af0 = *(const bf16x8*)&As[mt * 16 + ln][quad * 8];
            bf16x8 af1 = *(const bf16x8*)&As[mt * 16 + ln][32 + quad * 8];
            acc[mt] = __builtin_amdgcn_mfma_f32_16x16x32_bf16(af0, bf0, acc[mt], 0, 0, 0);
            acc[mt] = __builtin_amdgcn_mfma_f32_16x16x32_bf16(af1, bf1, acc[mt], 0, 0, 0);
        }
    }

    int col = n0 + wave * 16 + ln;
    float bz = bias[col];
#pragma unroll
    for (int mt = 0; mt < 4; mt++)
#pragma unroll
        for (int r = 0; r < 4; r++) {
            int row = m0 + mt * 16 + quad * 4 + r;
            out[(long)row * 1024 + col] = acc[mt][r] + bz;
        }
}

extern "C" void kernel_launch(void* const* d_in, const int* in_sizes, int n_in,
                              void* d_out, int out_size, void* d_ws, size_t ws_size,
                              hipStream_t stream) {
    const float* q    = (const float*)d_in[0];
    const float* k    = (const float*)d_in[1];
    const float* v    = (const float*)d_in[2];
    const float* Wo_w = (const float*)d_in[3];
    const float* Wo_b = (const float*)d_in[4];
    float* out = (float*)d_out;

    unsigned short* ctx = (unsigned short*)d_ws;           // [4096][1024]   8.4 MB
    unsigned short* wob = ctx + (size_t)4096 * 1024;       // [1024][1024]   2.1 MB
    unsigned short* kbb = wob + (size_t)1024 * 1024;       // [32][2048][64] 8.4 MB
    unsigned short* vtb = kbb + (size_t)32 * 2048 * 64;    // [32][64][2048] 8.4 MB
    float* Opart = (float*)(vtb + (size_t)32 * 2048 * 64); // [2][32][16][64][64] 16.8 MB
    float* lpart = Opart + (size_t)2 * 32 * 16 * 64 * 64;  // [2][32][16][64]  256 KB
    int*   flags = (int*)(lpart + (size_t)2 * 32 * 16 * 64); // [32][16]       2 KB

    prep_k<<<3073, 256, 0, stream>>>(k, v, Wo_w, kbb, vtb, wob, flags);
    attn_k<<<1536, 256, 0, stream>>>(q, kbb, vtb, ctx, Opart, lpart, flags);
    proj_k<<<1024, 256, 0, stream>>>(ctx, wob, Wo_b, out);
}

// Round 4
// 150.500 us; speedup vs baseline: 1.1095x; 1.0021x over previous
//
#include <hip/hip_runtime.h>

typedef __attribute__((ext_vector_type(8))) short bf16x8;
typedef __attribute__((ext_vector_type(4))) float f32x4;
typedef __attribute__((ext_vector_type(4))) unsigned int u32x4;
typedef __attribute__((ext_vector_type(2))) unsigned int u32x2;
typedef __attribute__((ext_vector_type(4))) unsigned short u16x4;

#define H_ 16
#define B_ 2
#define T_ 2048
#define DH_ 64
#define MD_ 1024

static __device__ inline unsigned short f2bf(float f) {  // round-nearest-even
    union { float f; unsigned u; } x; x.f = f;
    unsigned r = (x.u + 0x7fffu + ((x.u >> 16) & 1u)) >> 16;
    return (unsigned short)r;
}
// pack two fp32 -> two bf16 (truncation), lo in low short. 1 v_perm_b32.
static __device__ inline unsigned int pack_bf2(float lo, float hi) {
    return __builtin_amdgcn_perm(__float_as_uint(hi), __float_as_uint(lo), 0x07060302u);
}
static __device__ inline float fexp2(float x) {
#if __has_builtin(__builtin_amdgcn_exp2f)
    return __builtin_amdgcn_exp2f(x);   // raw v_exp_f32
#else
    return exp2f(x);
#endif
}

// ---------------------------------------------------------------------------
// Kernel 1: prep. blocks 0..1023: Wo fp32->bf16 (RNE). 1024..2047: K fp32->bf16
// (trunc, same layout). 2048..3071: V fp32 -> V^T bf16 [hb][dh][T] via LDS.
// block 3072: zero the merge flags (256 ints).
// ---------------------------------------------------------------------------
__global__ __launch_bounds__(256) void prep_k(const float* __restrict__ k,
                                              const float* __restrict__ v,
                                              const float* __restrict__ w,
                                              unsigned short* __restrict__ kb,
                                              unsigned short* __restrict__ vtb,
                                              unsigned short* __restrict__ wob,
                                              int* __restrict__ fl) {
    __shared__ __attribute__((aligned(16))) unsigned short vt64[64][64];
    const int blk = blockIdx.x;
    const int tid = threadIdx.x;
    if (blk < 1024) {
        int i = (blk * 256 + tid) * 4;
        f32x4 x = *(const f32x4*)(w + i);
        u16x4 y;
        y[0] = f2bf(x[0]); y[1] = f2bf(x[1]); y[2] = f2bf(x[2]); y[3] = f2bf(x[3]);
        *(u16x4*)(wob + i) = y;
    } else if (blk < 2048) {
        int j = blk - 1024;
        const int hb = j >> 5, s0 = (j & 31) * 64;
        const int row = tid >> 2, c = (tid & 3) * 16;
        const long off = (long)hb * (T_ * DH_) + (long)(s0 + row) * DH_ + c;
        const float* p = k + off;
        f32x4 a0 = *(const f32x4*)p;
        f32x4 a1 = *(const f32x4*)(p + 4);
        f32x4 a2 = *(const f32x4*)(p + 8);
        f32x4 a3 = *(const f32x4*)(p + 12);
        u32x4 w0, w1;
        w0[0] = pack_bf2(a0[0], a0[1]); w0[1] = pack_bf2(a0[2], a0[3]);
        w0[2] = pack_bf2(a1[0], a1[1]); w0[3] = pack_bf2(a1[2], a1[3]);
        w1[0] = pack_bf2(a2[0], a2[1]); w1[1] = pack_bf2(a2[2], a2[3]);
        w1[2] = pack_bf2(a3[0], a3[1]); w1[3] = pack_bf2(a3[2], a3[3]);
        *(u32x4*)(kb + off) = w0;
        *(u32x4*)(kb + off + 8) = w1;
    } else if (blk < 3072) {
        int j = blk - 2048;
        const int hb = j >> 5, s0 = (j & 31) * 64;
        const int vkp = tid & 31, vdg = tid >> 5;  // key-pair, dh-group
        const float* vp = v + (long)hb * (T_ * DH_) + (long)(s0 + 2 * vkp) * DH_ + vdg * 8;
        f32x4 va0 = *(const f32x4*)vp;
        f32x4 va1 = *(const f32x4*)(vp + 4);
        f32x4 vb0 = *(const f32x4*)(vp + DH_);
        f32x4 vb1 = *(const f32x4*)(vp + DH_ + 4);
#pragma unroll
        for (int jj = 0; jj < 4; jj++) {
            ((unsigned int*)&vt64[vdg * 8 + jj][0])[vkp]     = pack_bf2(va0[jj], vb0[jj]);
            ((unsigned int*)&vt64[vdg * 8 + 4 + jj][0])[vkp] = pack_bf2(va1[jj], vb1[jj]);
        }
        __syncthreads();
        const int dh = tid >> 2, kc = (tid & 3) * 16;
        u32x4 o0 = *(const u32x4*)&vt64[dh][kc];
        u32x4 o1 = *(const u32x4*)&vt64[dh][kc + 8];
        unsigned short* op = vtb + (long)hb * (DH_ * T_) + (long)dh * T_ + s0 + kc;
        *(u32x4*)op = o0;
        *(u32x4*)(op + 8) = o1;
    } else {
        for (int z = tid; z < 256; z += 256) fl[z] = 0;
    }
}

// ---------------------------------------------------------------------------
// Kernel 2: causal attention. 128-row q-tiles (wave = 32 q rows, two 16-row
// MFMA subtiles sharing each K/V fragment read -> 10.5 DS-cyc/q-row/step vs
// 18 before). Swapped-operand MFMA throughout (S^T = K.Q, O^T = V^T.P).
// 16 tiles/hb; tiles 8..15 split in two chunks; chunk multiset packs exactly
// into 32 CU-triples of 34 steps (8 types x 4 hb per XCD). Grid 768 = 3/CU.
// Merge protocol (agent-scope partials + flag, loser merges) as validated.
// ---------------------------------------------------------------------------
#define SE2(t, lo, hi) ((unsigned)((t) | ((lo) << 4) | ((hi) << 10)))
__constant__ unsigned sched24[3][8] = {
    // slot 0 (largest chunk of each triple-type A..H)
    { SE2(15,0,16), SE2(7,0,16), SE2(14,0,15), SE2(14,15,30),
      SE2(13,0,14), SE2(13,14,28), SE2(12,13,26), SE2(11,12,24) },
    // slot 1
    { SE2(15,16,32), SE2(6,0,14), SE2(12,0,13), SE2(10,0,11),
      SE2(10,11,22), SE2(9,0,10), SE2(11,0,12), SE2(5,0,12) },
    // slot 2
    { SE2(0,0,2), SE2(1,0,4), SE2(2,0,6), SE2(3,0,8),
      SE2(8,0,9), SE2(9,10,20), SE2(8,9,18), SE2(4,0,10) },
};

__global__ __launch_bounds__(256, 3) void attn_k(const float* __restrict__ q,
                                                 const unsigned short* __restrict__ kb,
                                                 const unsigned short* __restrict__ vtb,
                                                 unsigned short* __restrict__ ctx,
                                                 float* __restrict__ Op,
                                                 float* __restrict__ lp,
                                                 int* __restrict__ fl) {
    const int i = blockIdx.x;
    const int xcd = i & 7, j = i >> 3;            // per-XCD stream of 96 blocks
    const int cu = j & 31, slot = j >> 5;         // 32 CUs x 3 slots
    const int type = cu >> 2, hbl = cu & 3;
    const unsigned e = sched24[slot][type];
    const int t  = (int)(e & 15u);                // tile index 0..15 (128 rows)
    const int lo = (int)((e >> 4) & 63u);
    const int hi = (int)(e >> 10);
    const int hb = xcd * 4 + hbl;                 // K/V of 4 hb stay in this XCD's L2
    const int h = hb >> 1, b = hb & 1;
    const int tid = threadIdx.x;
    const int wave = tid >> 6, lane = tid & 63;
    const int ln = lane & 15, quad = lane >> 4;

    __shared__ __attribute__((aligned(16))) unsigned short kt[64][72];    // [key][dh]
    __shared__ __attribute__((aligned(16))) unsigned short vt[64][72];    // [dh][key]
    __shared__ __attribute__((aligned(16))) unsigned short pl[4][32][72]; // per-wave P [q][key]
    __shared__ int sh_who;

    const long kbase = (long)hb * (T_ * DH_);
    const long vbase = (long)hb * (DH_ * T_);
    const int q0w = t * 128 + wave * 32;          // wave's first q row
    const int srow = tid >> 2, sc = (tid & 3) * 16;

    // Q fragments for both 16-row subtiles (RNE, 0.125*log2(e) folded)
    bf16x8 qf00, qf01, qf10, qf11;
    {
        const float qs = 0.18033688011112042f;
        const float* qp0 = q + kbase + (long)(q0w + ln) * DH_ + quad * 8;
        const float* qp1 = qp0 + 16 * DH_;
        f32x4 a0 = *(const f32x4*)qp0;
        f32x4 a1 = *(const f32x4*)(qp0 + 4);
        f32x4 b0 = *(const f32x4*)(qp0 + 32);
        f32x4 b1 = *(const f32x4*)(qp0 + 36);
        f32x4 c0 = *(const f32x4*)qp1;
        f32x4 c1 = *(const f32x4*)(qp1 + 4);
        f32x4 d0 = *(const f32x4*)(qp1 + 32);
        f32x4 d1 = *(const f32x4*)(qp1 + 36);
#pragma unroll
        for (int z = 0; z < 4; z++) {
            qf00[z]   = (short)f2bf(a0[z] * qs);
            qf00[4+z] = (short)f2bf(a1[z] * qs);
            qf01[z]   = (short)f2bf(b0[z] * qs);
            qf01[4+z] = (short)f2bf(b1[z] * qs);
            qf10[z]   = (short)f2bf(c0[z] * qs);
            qf10[4+z] = (short)f2bf(c1[z] * qs);
            qf11[z]   = (short)f2bf(d0[z] * qs);
            qf11[4+z] = (short)f2bf(d1[z] * qs);
        }
    }

    // O^T accumulators: oTu[dt][r] = O[q = q0w + u*16 + ln][dh = dt*16+quad*4+r]
    f32x4 oT0[4], oT1[4];
#pragma unroll
    for (int z = 0; z < 4; z++) { oT0[z] = f32x4{0.f,0.f,0.f,0.f}; oT1[z] = f32x4{0.f,0.f,0.f,0.f}; }
    float lsum0 = 0.f, lsum1 = 0.f;

    // prefetch first step of this chunk
    u32x4 kr0, kr1, vr0, vr1;
    {
        const unsigned short* kp = kb + kbase + (long)(lo * 64 + srow) * DH_ + sc;
        kr0 = *(const u32x4*)kp; kr1 = *(const u32x4*)(kp + 8);
        const unsigned short* vp = vtb + vbase + (long)srow * T_ + lo * 64 + sc;
        vr0 = *(const u32x4*)vp; vr1 = *(const u32x4*)(vp + 8);
    }

#pragma unroll 1
    for (int step = lo; step < hi; step++) {
        __syncthreads();
        *(u32x4*)&kt[srow][sc]     = kr0;
        *(u32x4*)&kt[srow][sc + 8] = kr1;
        *(u32x4*)&vt[srow][sc]     = vr0;
        *(u32x4*)&vt[srow][sc + 8] = vr1;
        __syncthreads();

        if (step + 1 < hi) {
            const unsigned short* kp = kb + kbase + (long)((step + 1) * 64 + srow) * DH_ + sc;
            kr0 = *(const u32x4*)kp; kr1 = *(const u32x4*)(kp + 8);
            const unsigned short* vp = vtb + vbase + (long)srow * T_ + (step + 1) * 64 + sc;
            vr0 = *(const u32x4*)vp; vr1 = *(const u32x4*)(vp + 8);
        }

        if (step * 64 <= q0w + 31) {              // else: wave fully masked, skip compute
            const bool dmask = (step * 64 + 63 > q0w);   // diagonal touches this wave
            const int dbase = step * 64 + quad * 4 - q0w - ln;

            // QK^T (shared K-frags across both q-subtiles), exp2, mask, pack -> pl
#pragma unroll
            for (int nt = 0; nt < 4; nt++) {
                bf16x8 kf0 = *(const bf16x8*)&kt[nt * 16 + ln][quad * 8];
                bf16x8 kf1 = *(const bf16x8*)&kt[nt * 16 + ln][32 + quad * 8];
                f32x4 a0 = f32x4{0.f,0.f,0.f,0.f};
                a0 = __builtin_amdgcn_mfma_f32_16x16x32_bf16(kf0, qf00, a0, 0, 0, 0);
                a0 = __builtin_amdgcn_mfma_f32_16x16x32_bf16(kf1, qf01, a0, 0, 0, 0);
                f32x4 a1 = f32x4{0.f,0.f,0.f,0.f};
                a1 = __builtin_amdgcn_mfma_f32_16x16x32_bf16(kf0, qf10, a1, 0, 0, 0);
                a1 = __builtin_amdgcn_mfma_f32_16x16x32_bf16(kf1, qf11, a1, 0, 0, 0);
#pragma unroll
                for (int r = 0; r < 4; r++) { a0[r] = fexp2(a0[r]); a1[r] = fexp2(a1[r]); }
                if (dmask) {
#pragma unroll
                    for (int r = 0; r < 4; r++) {
                        if (dbase + nt * 16 + r > 0)  a0[r] = 0.f;
                        if (dbase + nt * 16 + r > 16) a1[r] = 0.f;
                    }
                }
                lsum0 += (a0[0] + a0[1]) + (a0[2] + a0[3]);
                lsum1 += (a1[0] + a1[1]) + (a1[2] + a1[3]);
                u32x2 w0, w1;
                w0[0] = pack_bf2(a0[0], a0[1]); w0[1] = pack_bf2(a0[2], a0[3]);
                w1[0] = pack_bf2(a1[0], a1[1]); w1[1] = pack_bf2(a1[2], a1[3]);
                *(u32x2*)&pl[wave][ln][nt * 16 + quad * 4]      = w0;
                *(u32x2*)&pl[wave][16 + ln][nt * 16 + quad * 4] = w1;
            }

            // per-wave buffer: in-wave DS ordering + lgkmcnt, no barrier needed
            bf16x8 pf00 = *(const bf16x8*)&pl[wave][ln][quad * 8];
            bf16x8 pf01 = *(const bf16x8*)&pl[wave][ln][32 + quad * 8];
            bf16x8 pf10 = *(const bf16x8*)&pl[wave][16 + ln][quad * 8];
            bf16x8 pf11 = *(const bf16x8*)&pl[wave][16 + ln][32 + quad * 8];

            // PV (shared V-frags): oTu[dt] += V^T . P_u
#pragma unroll
            for (int dt = 0; dt < 4; dt++) {
                bf16x8 vf0 = *(const bf16x8*)&vt[dt * 16 + ln][quad * 8];
                bf16x8 vf1 = *(const bf16x8*)&vt[dt * 16 + ln][32 + quad * 8];
                oT0[dt] = __builtin_amdgcn_mfma_f32_16x16x32_bf16(vf0, pf00, oT0[dt], 0, 0, 0);
                oT0[dt] = __builtin_amdgcn_mfma_f32_16x16x32_bf16(vf1, pf01, oT0[dt], 0, 0, 0);
                oT1[dt] = __builtin_amdgcn_mfma_f32_16x16x32_bf16(vf0, pf10, oT1[dt], 0, 0, 0);
                oT1[dt] = __builtin_amdgcn_mfma_f32_16x16x32_bf16(vf1, pf11, oT1[dt], 0, 0, 0);
            }
        }
    }

    // full row-sums (keys were split across quads)
    lsum0 += __shfl_xor(lsum0, 16); lsum0 += __shfl_xor(lsum0, 32);
    lsum1 += __shfl_xor(lsum1, 16); lsum1 += __shfl_xor(lsum1, 32);

    float rl0, rl1;
    if (t < 8) {
        rl0 = __builtin_amdgcn_rcpf(lsum0);
        rl1 = __builtin_amdgcn_rcpf(lsum1);
    } else {
        // split tile: publish partial in O^T slab [dh][q] (coalesced 64B per quad)
        const int c = (lo != 0) ? 1 : 0;
        const long slab = ((long)c * 32 + hb) * 8 + (t - 8);
        float* ob = Op + slab * 8192;
        const int ql0 = wave * 32 + ln, ql1 = ql0 + 16;
#pragma unroll
        for (int dt = 0; dt < 4; dt++)
#pragma unroll
            for (int r = 0; r < 4; r++) {
                const int dh = dt * 16 + quad * 4 + r;
                __hip_atomic_store(&ob[dh * 128 + ql0], oT0[dt][r],
                                   __ATOMIC_RELAXED, __HIP_MEMORY_SCOPE_AGENT);
                __hip_atomic_store(&ob[dh * 128 + ql1], oT1[dt][r],
                                   __ATOMIC_RELAXED, __HIP_MEMORY_SCOPE_AGENT);
            }
        if (quad == 0) {
            __hip_atomic_store(&lp[slab * 128 + ql0], lsum0,
                               __ATOMIC_RELAXED, __HIP_MEMORY_SCOPE_AGENT);
            __hip_atomic_store(&lp[slab * 128 + ql1], lsum1,
                               __ATOMIC_RELAXED, __HIP_MEMORY_SCOPE_AGENT);
        }
        __syncthreads();   // drains each wave's vmcnt -> partials visible at agent scope
        if (tid == 0)
            sh_who = __hip_atomic_fetch_add(&fl[hb * 8 + (t - 8)], 1,
                                            __ATOMIC_RELAXED, __HIP_MEMORY_SCOPE_AGENT);
        __syncthreads();
        if (sh_who != 1) return;   // first finisher exits; loser merges (block-uniform)
        const long slab2 = ((long)(c ^ 1) * 32 + hb) * 8 + (t - 8);
        const float* qb = Op + slab2 * 8192;
#pragma unroll
        for (int dt = 0; dt < 4; dt++)
#pragma unroll
            for (int r = 0; r < 4; r++) {
                const int dh = dt * 16 + quad * 4 + r;
                oT0[dt][r] += __hip_atomic_load(&qb[dh * 128 + ql0],
                                                __ATOMIC_RELAXED, __HIP_MEMORY_SCOPE_AGENT);
                oT1[dt][r] += __hip_atomic_load(&qb[dh * 128 + ql1],
                                                __ATOMIC_RELAXED, __HIP_MEMORY_SCOPE_AGENT);
            }
        lsum0 += __hip_atomic_load(&lp[slab2 * 128 + ql0],
                                   __ATOMIC_RELAXED, __HIP_MEMORY_SCOPE_AGENT);
        lsum1 += __hip_atomic_load(&lp[slab2 * 128 + ql1],
                                   __ATOMIC_RELAXED, __HIP_MEMORY_SCOPE_AGENT);
        rl0 = __builtin_amdgcn_rcpf(lsum0);
        rl1 = __builtin_amdgcn_rcpf(lsum1);
    }

    // epilogue: scale, pack bf16 (RNE), transpose via own-wave pl region
    // (in-wave DS ordering, no barrier), then coalesced 16B ctx stores.
#pragma unroll
    for (int dt = 0; dt < 4; dt++) {
        u16x4 y0, y1;
        y0[0] = f2bf(oT0[dt][0] * rl0); y0[1] = f2bf(oT0[dt][1] * rl0);
        y0[2] = f2bf(oT0[dt][2] * rl0); y0[3] = f2bf(oT0[dt][3] * rl0);
        y1[0] = f2bf(oT1[dt][0] * rl1); y1[1] = f2bf(oT1[dt][1] * rl1);
        y1[2] = f2bf(oT1[dt][2] * rl1); y1[3] = f2bf(oT1[dt][3] * rl1);
        *(u16x4*)&pl[wave][ln][dt * 16 + quad * 4]      = y0;
        *(u16x4*)&pl[wave][16 + ln][dt * 16 + quad * 4] = y1;
    }
    const int rr = lane >> 1, cc = (lane & 1) * 32;
    u32x4 z0 = *(const u32x4*)&pl[wave][rr][cc];
    u32x4 z1 = *(const u32x4*)&pl[wave][rr][cc + 8];
    u32x4 z2 = *(const u32x4*)&pl[wave][rr][cc + 16];
    u32x4 z3 = *(const u32x4*)&pl[wave][rr][cc + 24];
    unsigned short* cp = ctx + (long)(b * T_ + t * 128 + wave * 32 + rr) * MD_ + h * 64 + cc;
    *(u32x4*)cp = z0;
    *(u32x4*)(cp + 8) = z1;
    *(u32x4*)(cp + 16) = z2;
    *(u32x4*)(cp + 24) = z3;
}

// ---------------------------------------------------------------------------
// Kernel 3: projection GEMM. out[m][n] = ctx[m][:] . Wo[n][:] + bias[n]
// M=4096 N=1024 K=1024. BM=64 BN=64 BK=64 -> 1024 blocks (4/CU).
// XCD swizzle: each XCD owns 2 n-tiles (Wo slice 256 KB -> L2-resident).
// ---------------------------------------------------------------------------
__global__ __launch_bounds__(256, 4) void proj_k(const unsigned short* __restrict__ A,
                                                 const unsigned short* __restrict__ Bw,
                                                 const float* __restrict__ bias,
                                                 float* __restrict__ out) {
    const int i = blockIdx.x;
    const int n0 = ((i & 7) * 2 + ((i >> 3) & 1)) * 64;
    const int m0 = (i >> 4) * 64;
    const int tid = threadIdx.x;
    const int wave = tid >> 6, lane = tid & 63;
    const int ln = lane & 15, quad = lane >> 4;

    __shared__ __attribute__((aligned(16))) unsigned short As[64][72];
    __shared__ __attribute__((aligned(16))) unsigned short Bs[64][72];

    const int srow = tid >> 2, sc = (tid & 3) * 16;

    f32x4 acc[4];
#pragma unroll
    for (int z = 0; z < 4; z++) acc[z] = f32x4{0.f, 0.f, 0.f, 0.f};

    u32x4 ar0, ar1, br0, br1;
    {
        const unsigned short* ap = A + (long)(m0 + srow) * 1024 + sc;
        ar0 = *(const u32x4*)ap; ar1 = *(const u32x4*)(ap + 8);
        const unsigned short* bp = Bw + (long)(n0 + srow) * 1024 + sc;
        br0 = *(const u32x4*)bp; br1 = *(const u32x4*)(bp + 8);
    }

#pragma unroll 1
    for (int ks = 0; ks < 1024; ks += 64) {
        __syncthreads();
        *(u32x4*)&As[srow][sc]     = ar0;
        *(u32x4*)&As[srow][sc + 8] = ar1;
        *(u32x4*)&Bs[srow][sc]     = br0;
        *(u32x4*)&Bs[srow][sc + 8] = br1;
        __syncthreads();

        if (ks + 64 < 1024) {
            const unsigned short* ap = A + (long)(m0 + srow) * 1024 + ks + 64 + sc;
            ar0 = *(const u32x4*)ap; ar1 = *(const u32x4*)(ap + 8);
            const unsigned short* bp = Bw + (long)(n0 + srow) * 1024 + ks + 64 + sc;
            br0 = *(const u32x4*)bp; br1 = *(const u32x4*)(bp + 8);
        }

        bf16x8 bf0 = *(const bf16x8*)&Bs[wave * 16 + ln][quad * 8];
        bf16x8 bf1 = *(const bf16x8*)&Bs[wave * 16 + ln][32 + quad * 8];
#pragma unroll
        for (int mt = 0; mt < 4; mt++) {
            bf16x8 af0 = *(const bf16x8*)&As[mt * 16 + ln][quad * 8];
            bf16x8 af1 = *(const bf16x8*)&As[mt * 16 + ln][32 + quad * 8];
            acc[mt] = __builtin_amdgcn_mfma_f32_16x16x32_bf16(af0, bf0, acc[mt], 0, 0, 0);
            acc[mt] = __builtin_amdgcn_mfma_f32_16x16x32_bf16(af1, bf1, acc[mt], 0, 0, 0);
        }
    }

    int col = n0 + wave * 16 + ln;
    float bz = bias[col];
#pragma unroll
    for (int mt = 0; mt < 4; mt++)
#pragma unroll
        for (int r = 0; r < 4; r++) {
            int row = m0 + mt * 16 + quad * 4 + r;
            out[(long)row * 1024 + col] = acc[mt][r] + bz;
        }
}

extern "C" void kernel_launch(void* const* d_in, const int* in_sizes, int n_in,
                              void* d_out, int out_size, void* d_ws, size_t ws_size,
                              hipStream_t stream) {
    const float* q    = (const float*)d_in[0];
    const float* k    = (const float*)d_in[1];
    const float* v    = (const float*)d_in[2];
    const float* Wo_w = (const float*)d_in[3];
    const float* Wo_b = (const float*)d_in[4];
    float* out = (float*)d_out;

    unsigned short* ctx = (unsigned short*)d_ws;           // [4096][1024]   8.4 MB
    unsigned short* wob = ctx + (size_t)4096 * 1024;       // [1024][1024]   2.1 MB
    unsigned short* kbb = wob + (size_t)1024 * 1024;       // [32][2048][64] 8.4 MB
    unsigned short* vtb = kbb + (size_t)32 * 2048 * 64;    // [32][64][2048] 8.4 MB
    float* Opart = (float*)(vtb + (size_t)32 * 2048 * 64); // [2][32][8][64][128] 16.8 MB
    float* lpart = Opart + (size_t)2 * 32 * 8 * 64 * 128;  // [2][32][8][128]  256 KB
    int*   flags = (int*)(lpart + (size_t)2 * 32 * 8 * 128); // [32][8]        1 KB

    prep_k<<<3073, 256, 0, stream>>>(k, v, Wo_w, kbb, vtb, wob, flags);
    attn_k<<<768, 256, 0, stream>>>(q, kbb, vtb, ctx, Opart, lpart, flags);
    proj_k<<<1024, 256, 0, stream>>>(ctx, wob, Wo_b, out);
}